// Round 4
// baseline (186.813 us; speedup 1.0000x reference)
//
#include <hip/hip_runtime.h>
#include <hip/hip_cooperative_groups.h>
#include <math.h>

namespace cg = cooperative_groups;

#define N 512
#define SIGMA 0.5f
#define EPS 1e-7f

typedef __attribute__((ext_vector_type(8))) short bf16x8;
typedef __attribute__((ext_vector_type(4))) float f32x4;

__device__ __forceinline__ unsigned short f2bf(float x) {
    unsigned int b = __float_as_uint(x);
    b += 0x7FFFu + ((b >> 16) & 1u);   // RNE; inputs finite
    return (unsigned short)(b >> 16);
}
__device__ __forceinline__ float bf2f(unsigned short h) {
    return __uint_as_float((unsigned int)h << 16);
}

// ---------------------------------------------------------------------------
// Single cooperative kernel. Grid 256 x 512. Block b owns rows b and b+256.
//  P1: convert rows b, b+256 to bf16 + sq-norms (global)     [all blocks]
//  --- grid.sync ---
//  P2: each block computes the two 16-row Gram slabs containing its rows
//      (16x redundant MFMA, ~2us total) and extracts its own F-rows to LDS.
//  P3: per-row softmax + denom (float4 LDS broadcast loop) + loss atomic.
// ---------------------------------------------------------------------------
__global__ __launch_bounds__(512, 2)
void fused_kernel(const float* __restrict__ feat,
                  const float* __restrict__ label,
                  unsigned short* __restrict__ featb,
                  float* __restrict__ sqn,
                  float* __restrict__ out) {
    const int b = blockIdx.x;          // 0..255
    const int t = threadIdx.x;         // 0..511
    const int wave = t >> 6, lane = t & 63;

    __shared__ __align__(16) float FrowA[N];   // dot(row b, :)
    __shared__ __align__(16) float FrowB[N];   // dot(row b+256, :)
    __shared__ __align__(16) float Rs[N];
    __shared__ __align__(16) float Ss[N];
    __shared__ float red0[8], red1[8];

    const int rA = b, rB = b + 256;

    // ---- P1: convert + sqnorms ----
    {
        float v0 = feat[(size_t)rA * N + t];
        float v1 = feat[(size_t)rB * N + t];
        unsigned short h0 = f2bf(v0), h1 = f2bf(v1);
        featb[(size_t)rA * N + t] = h0;
        featb[(size_t)rB * N + t] = h1;
        float q0 = bf2f(h0); q0 *= q0;
        float q1 = bf2f(h1); q1 *= q1;
        #pragma unroll
        for (int off = 32; off > 0; off >>= 1) {
            q0 += __shfl_xor(q0, off);
            q1 += __shfl_xor(q1, off);
        }
        if (lane == 0) { red0[wave] = q0; red1[wave] = q1; }
        __syncthreads();
        if (t == 0) {
            float s0 = 0.f, s1 = 0.f;
            #pragma unroll
            for (int w = 0; w < 8; ++w) { s0 += red0[w]; s1 += red1[w]; }
            sqn[rA] = s0; sqn[rB] = s1;
            if (b == 0) out[0] = 0.f;
        }
    }
    __threadfence();
    cg::this_grid().sync();

    // ---- P2: Gram slabs via MFMA; extract own rows into LDS ----
    {
        const int rl = b & 15;                         // row-in-slab (same for rA, rB)
        const int slab = (wave < 4) ? (rA & ~15) : ((rB & ~15));
        float* Frow = (wave < 4) ? FrowA : FrowB;
        const int w4 = wave & 3;
        const int m = lane & 15;
        const int kb = (lane >> 4) * 8;

        const unsigned short* abase = featb + (size_t)(slab + m) * N + kb;
        bf16x8 afr[16];
        #pragma unroll
        for (int k0 = 0; k0 < 16; ++k0)
            afr[k0] = *(const bf16x8*)(abase + k0 * 32);

        #pragma unroll
        for (int j = 0; j < 8; ++j) {
            const int c0 = (w4 + j * 4) * 16;          // this wave's col-tile
            const unsigned short* bbase = featb + (size_t)(c0 + m) * N + kb;
            f32x4 acc = {0.f, 0.f, 0.f, 0.f};
            #pragma unroll
            for (int k0 = 0; k0 < 16; ++k0) {
                bf16x8 bfr = *(const bf16x8*)(bbase + k0 * 32);
                acc = __builtin_amdgcn_mfma_f32_16x16x32_bf16(afr[k0], bfr, acc, 0, 0, 0);
            }
            // C/D mapping (HW-validated round 2): col=lane&15, row=(lane>>4)*4+reg
            if ((lane >> 4) == (rl >> 2))
                Frow[c0 + m] = acc[rl & 3];
        }
        __syncthreads();
    }

    // ---- P3: two rows, softmax + denom + loss ----
    float blocksum = 0.f;   // meaningful on t==0 only
    #pragma unroll 1
    for (int rr = 0; rr < 2; ++rr) {
        const int i = (rr == 0) ? rA : rB;
        const float* Frow = (rr == 0) ? FrowA : FrowB;
        const float li = label[i];
        const float sqi = sqn[i];

        const float dotc = Frow[t];
        const float sqc = sqn[t];
        const float F = (t == i) ? 0.f
                      : -SIGMA * sqrtf(fmaxf(sqi + sqc - 2.f * dotc, 0.f));
        const float Rk = fabsf(li - label[t]);
        Rs[t] = Rk;
        const float e = __expf(F);      // row max is exactly 0 -> no max pass

        float z = e;
        #pragma unroll
        for (int off = 32; off > 0; off >>= 1) z += __shfl_xor(z, off);
        if (lane == 0) red0[wave] = z;
        __syncthreads();
        const float Z = red0[0] + red0[1] + red0[2] + red0[3] +
                        red0[4] + red0[5] + red0[6] + red0[7];
        float S = e / Z;
        if (t == i) S = 0.f;            // exclude j==i from all denom sums
        Ss[t] = S;
        __syncthreads();

        float denom = 0.f;
        const float4* R4 = (const float4*)Rs;
        const float4* S4 = (const float4*)Ss;
        #pragma unroll 8
        for (int j4 = 0; j4 < N / 4; ++j4) {
            float4 r = R4[j4];
            float4 sv = S4[j4];
            denom += (r.x >= Rk) ? sv.x : 0.f;
            denom += (r.y >= Rk) ? sv.y : 0.f;
            denom += (r.z >= Rk) ? sv.z : 0.f;
            denom += (r.w >= Rk) ? sv.w : 0.f;
        }

        float part = (t == i) ? 0.f : (F - __logf(denom + EPS));
        #pragma unroll
        for (int off = 32; off > 0; off >>= 1) part += __shfl_xor(part, off);
        if (lane == 0) red1[wave] = part;
        __syncthreads();
        if (t == 0) {
            blocksum += red1[0] + red1[1] + red1[2] + red1[3] +
                        red1[4] + red1[5] + red1[6] + red1[7];
        }
        __syncthreads();               // Rs/Ss/red reuse in next iteration
    }
    if (t == 0)
        atomicAdd(out, blocksum * (-1.f / ((float)N * (float)(N - 1))));
}

// ---------------------------------------------------------------------------
extern "C" void kernel_launch(void* const* d_in, const int* in_sizes, int n_in,
                              void* d_out, int out_size, void* d_ws, size_t ws_size,
                              hipStream_t stream) {
    const float* feature = (const float*)d_in[0];   // [512, 512] f32
    const float* label   = (const float*)d_in[1];   // [512, 1]  f32
    float* out = (float*)d_out;

    unsigned short* featb = (unsigned short*)d_ws;                  // 512 KB
    float* sqn = (float*)((char*)d_ws + (size_t)N * N * sizeof(unsigned short));

    void* args[] = { (void*)&feature, (void*)&label, (void*)&featb,
                     (void*)&sqn, (void*)&out };
    hipLaunchCooperativeKernel((const void*)fused_kernel,
                               dim3(256), dim3(512), args, 0, stream);
}

// Round 5
// 159.672 us; speedup vs baseline: 1.1700x; 1.1700x over previous
//
#include <hip/hip_runtime.h>
#include <hip/hip_cooperative_groups.h>
#include <math.h>

namespace cg = cooperative_groups;

#define N 512
#define SIGMA 0.5f
#define EPS 1e-7f

typedef __attribute__((ext_vector_type(8))) short bf16x8;
typedef __attribute__((ext_vector_type(4))) float f32x4;

__device__ __forceinline__ unsigned short f2bf(float x) {
    unsigned int b = __float_as_uint(x);
    b += 0x7FFFu + ((b >> 16) & 1u);   // RNE; inputs finite
    return (unsigned short)(b >> 16);
}
__device__ __forceinline__ float bf2f(unsigned short h) {
    return __uint_as_float((unsigned int)h << 16);
}

// ---------------------------------------------------------------------------
// Single cooperative kernel. Grid 256 x 512. Block b owns rows b and b+256.
//  P1: convert rows b, b+256 to bf16 + sq-norms         [all blocks]
//  --- grid.sync ---
//  P2: MFMA Gram slabs (16x redundant), k-outer / j-inner, ALL vector-array
//      indices compile-time constant (no scratch — rule #20).
//  P3: per-row softmax + denom (float4 LDS broadcast loop) + loss atomic.
// ---------------------------------------------------------------------------
__global__ __launch_bounds__(512, 2)
void fused_kernel(const float* __restrict__ feat,
                  const float* __restrict__ label,
                  unsigned short* __restrict__ featb,
                  float* __restrict__ sqn,
                  float* __restrict__ out) {
    const int b = blockIdx.x;          // 0..255
    const int t = threadIdx.x;         // 0..511
    const int wave = t >> 6, lane = t & 63;

    __shared__ __align__(16) float FrowA[N];   // dot(row b, :)
    __shared__ __align__(16) float FrowB[N];   // dot(row b+256, :)
    __shared__ __align__(16) float Rs[N];
    __shared__ __align__(16) float Ss[N];
    __shared__ float red0[8], red1[8];

    const int rA = b, rB = b + 256;

    // ---- P1: convert + sqnorms ----
    {
        float v0 = feat[(size_t)rA * N + t];
        float v1 = feat[(size_t)rB * N + t];
        unsigned short h0 = f2bf(v0), h1 = f2bf(v1);
        featb[(size_t)rA * N + t] = h0;
        featb[(size_t)rB * N + t] = h1;
        float q0 = bf2f(h0); q0 *= q0;
        float q1 = bf2f(h1); q1 *= q1;
        #pragma unroll
        for (int off = 32; off > 0; off >>= 1) {
            q0 += __shfl_xor(q0, off);
            q1 += __shfl_xor(q1, off);
        }
        if (lane == 0) { red0[wave] = q0; red1[wave] = q1; }
        __syncthreads();
        if (t == 0) {
            float s0 = 0.f, s1 = 0.f;
            #pragma unroll
            for (int w = 0; w < 8; ++w) { s0 += red0[w]; s1 += red1[w]; }
            sqn[rA] = s0; sqn[rB] = s1;
            if (b == 0) out[0] = 0.f;
        }
    }
    __threadfence();
    cg::this_grid().sync();

    // ---- P2: Gram slabs via MFMA, k-outer / j-inner, no local arrays ----
    {
        const int rl = b & 15;                       // row-in-slab (rA and rB share it)
        const int slab = (wave < 4) ? (rA & ~15) : (rB & ~15);
        float* Frow = (wave < 4) ? FrowA : FrowB;
        const int w4 = wave & 3;                     // wave's col-tile phase
        const int m = lane & 15;
        const int kb = (lane >> 4) * 8;

        const unsigned short* abase = featb + (size_t)(slab + m) * N + kb;
        const unsigned short* bbase = featb + (size_t)m * N + kb;

        f32x4 acc0 = {0.f,0.f,0.f,0.f}, acc1 = {0.f,0.f,0.f,0.f},
              acc2 = {0.f,0.f,0.f,0.f}, acc3 = {0.f,0.f,0.f,0.f},
              acc4 = {0.f,0.f,0.f,0.f}, acc5 = {0.f,0.f,0.f,0.f},
              acc6 = {0.f,0.f,0.f,0.f}, acc7 = {0.f,0.f,0.f,0.f};

        // col-tile j covers Gram columns (w4 + j*4)*16 .. +15
        #define BPTR(j) (bbase + (size_t)((w4 + (j) * 4) * 16) * N)

        #pragma unroll 2
        for (int k0 = 0; k0 < 16; ++k0) {
            const int ko = k0 * 32;
            bf16x8 a = *(const bf16x8*)(abase + ko);
            acc0 = __builtin_amdgcn_mfma_f32_16x16x32_bf16(a, *(const bf16x8*)(BPTR(0) + ko), acc0, 0, 0, 0);
            acc1 = __builtin_amdgcn_mfma_f32_16x16x32_bf16(a, *(const bf16x8*)(BPTR(1) + ko), acc1, 0, 0, 0);
            acc2 = __builtin_amdgcn_mfma_f32_16x16x32_bf16(a, *(const bf16x8*)(BPTR(2) + ko), acc2, 0, 0, 0);
            acc3 = __builtin_amdgcn_mfma_f32_16x16x32_bf16(a, *(const bf16x8*)(BPTR(3) + ko), acc3, 0, 0, 0);
            acc4 = __builtin_amdgcn_mfma_f32_16x16x32_bf16(a, *(const bf16x8*)(BPTR(4) + ko), acc4, 0, 0, 0);
            acc5 = __builtin_amdgcn_mfma_f32_16x16x32_bf16(a, *(const bf16x8*)(BPTR(5) + ko), acc5, 0, 0, 0);
            acc6 = __builtin_amdgcn_mfma_f32_16x16x32_bf16(a, *(const bf16x8*)(BPTR(6) + ko), acc6, 0, 0, 0);
            acc7 = __builtin_amdgcn_mfma_f32_16x16x32_bf16(a, *(const bf16x8*)(BPTR(7) + ko), acc7, 0, 0, 0);
        }

        // D-layout (HW-validated): col = lane&15, row = (lane>>4)*4 + reg.
        // Extract row rl with STATIC acc indices (3 cndmask), store to LDS.
        const int sel = rl & 3;
        if ((lane >> 4) == (rl >> 2)) {
            #define EXTRACT(j, accJ) do { \
                float v_ = (sel == 0) ? accJ[0] : (sel == 1) ? accJ[1] \
                         : (sel == 2) ? accJ[2] : accJ[3]; \
                Frow[(w4 + (j) * 4) * 16 + m] = v_; } while (0)
            EXTRACT(0, acc0); EXTRACT(1, acc1); EXTRACT(2, acc2); EXTRACT(3, acc3);
            EXTRACT(4, acc4); EXTRACT(5, acc5); EXTRACT(6, acc6); EXTRACT(7, acc7);
            #undef EXTRACT
        }
        #undef BPTR
        __syncthreads();
    }

    // ---- P3: two rows, softmax + denom + loss ----
    float blocksum = 0.f;   // meaningful on t==0 only
    #pragma unroll 1
    for (int rr = 0; rr < 2; ++rr) {
        const int i = (rr == 0) ? rA : rB;
        const float* Frow = (rr == 0) ? FrowA : FrowB;
        const float li = label[i];
        const float sqi = sqn[i];

        const float dotc = Frow[t];
        const float sqc = sqn[t];
        const float F = (t == i) ? 0.f
                      : -SIGMA * sqrtf(fmaxf(sqi + sqc - 2.f * dotc, 0.f));
        const float Rk = fabsf(li - label[t]);
        Rs[t] = Rk;
        const float e = __expf(F);      // row max is exactly 0 -> no max pass

        float z = e;
        #pragma unroll
        for (int off = 32; off > 0; off >>= 1) z += __shfl_xor(z, off);
        if (lane == 0) red0[wave] = z;
        __syncthreads();
        const float Z = red0[0] + red0[1] + red0[2] + red0[3] +
                        red0[4] + red0[5] + red0[6] + red0[7];
        float S = e / Z;
        if (t == i) S = 0.f;            // exclude j==i from all denom sums
        Ss[t] = S;
        __syncthreads();

        float denom = 0.f;
        const float4* R4 = (const float4*)Rs;
        const float4* S4 = (const float4*)Ss;
        #pragma unroll 8
        for (int j4 = 0; j4 < N / 4; ++j4) {
            float4 r = R4[j4];
            float4 sv = S4[j4];
            denom += (r.x >= Rk) ? sv.x : 0.f;
            denom += (r.y >= Rk) ? sv.y : 0.f;
            denom += (r.z >= Rk) ? sv.z : 0.f;
            denom += (r.w >= Rk) ? sv.w : 0.f;
        }

        float part = (t == i) ? 0.f : (F - __logf(denom + EPS));
        #pragma unroll
        for (int off = 32; off > 0; off >>= 1) part += __shfl_xor(part, off);
        if (lane == 0) red1[wave] = part;
        __syncthreads();
        if (t == 0) {
            blocksum += red1[0] + red1[1] + red1[2] + red1[3] +
                        red1[4] + red1[5] + red1[6] + red1[7];
        }
        __syncthreads();               // LDS reuse in next iteration
    }
    if (t == 0)
        atomicAdd(out, blocksum * (-1.f / ((float)N * (float)(N - 1))));
}

// ---------------------------------------------------------------------------
extern "C" void kernel_launch(void* const* d_in, const int* in_sizes, int n_in,
                              void* d_out, int out_size, void* d_ws, size_t ws_size,
                              hipStream_t stream) {
    const float* feature = (const float*)d_in[0];   // [512, 512] f32
    const float* label   = (const float*)d_in[1];   // [512, 1]  f32
    float* out = (float*)d_out;

    unsigned short* featb = (unsigned short*)d_ws;                  // 512 KB
    float* sqn = (float*)((char*)d_ws + (size_t)N * N * sizeof(unsigned short));

    void* args[] = { (void*)&feature, (void*)&label, (void*)&featb,
                     (void*)&sqn, (void*)&out };
    hipLaunchCooperativeKernel((const void*)fused_kernel,
                               dim3(256), dim3(512), args, 0, stream);
}

// Round 6
// 83.985 us; speedup vs baseline: 2.2244x; 1.9012x over previous
//
#include <hip/hip_runtime.h>
#include <math.h>

#define N 512
#define SIGMA 0.5f
#define EPS 1e-7f

typedef __attribute__((ext_vector_type(8))) short bf16x8;
typedef __attribute__((ext_vector_type(4))) float f32x4;

__device__ __forceinline__ unsigned short f2bf(float x) {
    unsigned int b = __float_as_uint(x);
    b += 0x7FFFu + ((b >> 16) & 1u);   // RNE; inputs finite
    return (unsigned short)(b >> 16);
}
__device__ __forceinline__ float bf2f(unsigned short h) {
    return __uint_as_float((unsigned int)h << 16);
}

// ---------------------------------------------------------------------------
// Kernel 1: fused fp32->bf16 convert + Gram + F-transform. One wave per
// 16x16 output tile, grid 32x32. Rows are converted redundantly in-register
// (deterministic, bitwise-consistent across blocks); sq-norms computed from
// the rounded values via quartet shfl reduction. No featb/sqn globals.
// ---------------------------------------------------------------------------
__global__ __launch_bounds__(64)
void fmatc_kernel(const float* __restrict__ feat,
                  float* __restrict__ Fm,
                  float* __restrict__ out) {
    const int r0 = blockIdx.y * 16;
    const int c0 = blockIdx.x * 16;
    const int lane = threadIdx.x;      // 0..63
    const int m = lane & 15;           // row index within tile (A and B sides)
    const int g = lane >> 4;           // k-group 0..3
    const int kb = g * 8;              // this lane's k-base within a 32-chunk

    if (r0 == 0 && c0 == 0 && lane == 0) out[0] = 0.f;  // zero loss accum

    const float* arow = feat + (size_t)(r0 + m) * N + kb;
    const float* brow = feat + (size_t)(c0 + m) * N + kb;

    f32x4 acc = {0.f, 0.f, 0.f, 0.f};
    float sqa = 0.f, sqb = 0.f;

    #pragma unroll
    for (int k0 = 0; k0 < 16; ++k0) {
        const int ko = k0 * 32;
        float4 a0 = *(const float4*)(arow + ko);
        float4 a1 = *(const float4*)(arow + ko + 4);
        float4 b0 = *(const float4*)(brow + ko);
        float4 b1 = *(const float4*)(brow + ko + 4);

        bf16x8 af, bv;
        af[0] = (short)f2bf(a0.x); af[1] = (short)f2bf(a0.y);
        af[2] = (short)f2bf(a0.z); af[3] = (short)f2bf(a0.w);
        af[4] = (short)f2bf(a1.x); af[5] = (short)f2bf(a1.y);
        af[6] = (short)f2bf(a1.z); af[7] = (short)f2bf(a1.w);
        bv[0] = (short)f2bf(b0.x); bv[1] = (short)f2bf(b0.y);
        bv[2] = (short)f2bf(b0.z); bv[3] = (short)f2bf(b0.w);
        bv[4] = (short)f2bf(b1.x); bv[5] = (short)f2bf(b1.y);
        bv[6] = (short)f2bf(b1.z); bv[7] = (short)f2bf(b1.w);

        // sq-norms of the ROUNDED values (consistent with the MFMA dots)
        #pragma unroll
        for (int e = 0; e < 8; ++e) {
            float ra = bf2f((unsigned short)af[e]); sqa += ra * ra;
            float rb = bf2f((unsigned short)bv[e]); sqb += rb * rb;
        }

        acc = __builtin_amdgcn_mfma_f32_16x16x32_bf16(af, bv, acc, 0, 0, 0);
    }

    // quartet reduce over lanes {m, m+16, m+32, m+48}: full-row sums
    sqa += __shfl_xor(sqa, 16); sqa += __shfl_xor(sqa, 32);
    sqb += __shfl_xor(sqb, 16); sqb += __shfl_xor(sqb, 32);

    // D-layout (HW-validated rounds 2-5): col = lane&15, row = (lane>>4)*4+reg
    const int col = c0 + m;
    const int rowb = g * 4;
    #pragma unroll
    for (int r = 0; r < 4; ++r) {
        const int row = r0 + rowb + r;
        const float sqr_ = __shfl(sqa, rowb + r);  // norm of row r0+rowb+r
        float sq = sqr_ + sqb - 2.f * acc[r];
        float v = (row == col) ? 0.f : -SIGMA * sqrtf(fmaxf(sq, 0.f));
        Fm[(size_t)row * N + col] = v;
    }
}

// ---------------------------------------------------------------------------
// Kernel 2: per-row fused softmax + denom + loss (round-2 verbatim — best
// measured). One block (512 threads) per row i; thread t owns column t.
// Row max is exactly 0 (diag F = 0, off-diag < 0) -> no max pass.
// ---------------------------------------------------------------------------
__global__ __launch_bounds__(512, 4)
void row_kernel(const float* __restrict__ Fm,
                const float* __restrict__ label,
                float* __restrict__ out) {
    const int i = blockIdx.x;
    const int t = threadIdx.x;   // 0..511
    const int wave = t >> 6, lane = t & 63;

    __shared__ __align__(16) float Rs[N];
    __shared__ __align__(16) float Ss[N];
    __shared__ float red[8];

    const float li = label[i];
    const float f = Fm[(size_t)i * N + t];
    const float Rk = fabsf(li - label[t]);
    Rs[t] = Rk;

    const float e = __expf(f);

    // Z = sum_j exp(f_j) (includes diagonal, exp(0)=1)
    float s = e;
    #pragma unroll
    for (int off = 32; off > 0; off >>= 1) s += __shfl_xor(s, off);
    if (lane == 0) red[wave] = s;
    __syncthreads();
    const float Z = red[0] + red[1] + red[2] + red[3] +
                    red[4] + red[5] + red[6] + red[7];

    float S = e / Z;
    if (t == i) S = 0.f;         // exclude j==i from all denom sums
    Ss[t] = S;
    __syncthreads();

    // denom[k=t] = sum_j [R[j] >= R[k]] * S[j], float4 LDS broadcasts
    float denom = 0.f;
    const float4* R4 = (const float4*)Rs;
    const float4* S4 = (const float4*)Ss;
    #pragma unroll 16
    for (int j4 = 0; j4 < N / 4; ++j4) {
        float4 r = R4[j4];
        float4 sv = S4[j4];
        denom += (r.x >= Rk) ? sv.x : 0.f;
        denom += (r.y >= Rk) ? sv.y : 0.f;
        denom += (r.z >= Rk) ? sv.z : 0.f;
        denom += (r.w >= Rk) ? sv.w : 0.f;
    }

    float part = (t == i) ? 0.f : (f - __logf(denom + EPS));

    #pragma unroll
    for (int off = 32; off > 0; off >>= 1) part += __shfl_xor(part, off);
    if (lane == 0) red[wave] = part;
    __syncthreads();
    if (t == 0) {
        float tot = red[0] + red[1] + red[2] + red[3] +
                    red[4] + red[5] + red[6] + red[7];
        atomicAdd(out, tot * (-1.f / ((float)N * (float)(N - 1))));
    }
}

// ---------------------------------------------------------------------------
extern "C" void kernel_launch(void* const* d_in, const int* in_sizes, int n_in,
                              void* d_out, int out_size, void* d_ws, size_t ws_size,
                              hipStream_t stream) {
    const float* feature = (const float*)d_in[0];   // [512, 512] f32
    const float* label   = (const float*)d_in[1];   // [512, 1]  f32
    float* out = (float*)d_out;

    float* Fm = (float*)d_ws;                       // N*N f32 (1 MB)

    {
        dim3 grid(N / 16, N / 16);
        fmatc_kernel<<<grid, 64, 0, stream>>>(feature, Fm, out);
    }
    row_kernel<<<N, N, 0, stream>>>(Fm, label, out);
}

// Round 7
// 77.512 us; speedup vs baseline: 2.4101x; 1.0835x over previous
//
#include <hip/hip_runtime.h>
#include <math.h>

#define N 512
#define SIGMA 0.5f
#define EPS 1e-7f

typedef __attribute__((ext_vector_type(8))) short bf16x8;
typedef __attribute__((ext_vector_type(4))) float f32x4;

__device__ __forceinline__ unsigned short f2bf(float x) {
    unsigned int b = __float_as_uint(x);
    b += 0x7FFFu + ((b >> 16) & 1u);   // RNE; inputs finite
    return (unsigned short)(b >> 16);
}
__device__ __forceinline__ float bf2f(unsigned short h) {
    return __uint_as_float((unsigned int)h << 16);
}

// ---------------------------------------------------------------------------
// Kernel 1 (R2 verbatim): fp32 -> bf16 convert + sq-norms of rounded values.
// One wave per row; also zeroes the loss accumulator.
// ---------------------------------------------------------------------------
__global__ void convert_kernel(const float* __restrict__ feat,
                               unsigned short* __restrict__ featb,
                               float* __restrict__ sqn,
                               float* __restrict__ out) {
    const int row = blockIdx.x;
    const int lane = threadIdx.x;            // 0..63
    if (row == 0 && lane == 0) out[0] = 0.f; // zero loss accumulator

    const float* f = feat + (size_t)row * N;
    unsigned short* fb = featb + (size_t)row * N;
    float s = 0.f;
    #pragma unroll
    for (int sweep = 0; sweep < 2; ++sweep) {
        int c = sweep * 256 + lane * 4;
        float4 v = *(const float4*)(f + c);
        unsigned short b0 = f2bf(v.x), b1 = f2bf(v.y),
                       b2 = f2bf(v.z), b3 = f2bf(v.w);
        *(ushort4*)(fb + c) = make_ushort4(b0, b1, b2, b3);
        float r0 = bf2f(b0), r1 = bf2f(b1), r2 = bf2f(b2), r3 = bf2f(b3);
        s += r0 * r0 + r1 * r1 + r2 * r2 + r3 * r3;
    }
    #pragma unroll
    for (int off = 32; off > 0; off >>= 1) s += __shfl_down(s, off);
    if (lane == 0) sqn[row] = s;
}

// ---------------------------------------------------------------------------
// Kernel 2: symmetric F via bf16 MFMA. 528 blocks = lower-triangle 16x16
// tiles (bi >= bj). Each wave computes one tile and writes it twice:
//  - row-major scalar stores (16 consecutive cols per lane group: coalesced)
//  - transposed float4 store: acc[0..3] are 4 consecutive ROWS at one col,
//    i.e. contiguous at Fm[col*N + rowb] (16B aligned).
// Diagonal tiles double-write identical values (benign).
// ---------------------------------------------------------------------------
__global__ __launch_bounds__(64)
void fmat_sym_kernel(const unsigned short* __restrict__ featb,
                     const float* __restrict__ sqn,
                     float* __restrict__ Fm) {
    const int id = blockIdx.x;               // 0..527
    // triangular decode: bi = largest with bi*(bi+1)/2 <= id
    int bi = (int)((sqrtf(8.f * (float)id + 1.f) - 1.f) * 0.5f);
    while ((bi + 1) * (bi + 2) / 2 <= id) ++bi;
    while (bi * (bi + 1) / 2 > id) --bi;
    const int bj = id - bi * (bi + 1) / 2;   // bj <= bi

    const int r0 = bi * 16;
    const int c0 = bj * 16;
    const int lane = threadIdx.x;
    const int m = lane & 15;
    const int kb = (lane >> 4) * 8;

    const unsigned short* arow = featb + (size_t)(r0 + m) * N + kb;
    const unsigned short* brow = featb + (size_t)(c0 + m) * N + kb;

    f32x4 acc = {0.f, 0.f, 0.f, 0.f};
    #pragma unroll
    for (int k0 = 0; k0 < N; k0 += 32) {
        bf16x8 a = *(const bf16x8*)(arow + k0);
        bf16x8 b = *(const bf16x8*)(brow + k0);
        acc = __builtin_amdgcn_mfma_f32_16x16x32_bf16(a, b, acc, 0, 0, 0);
    }

    // D-layout (HW-validated rounds 2-6): col = lane&15, row = (lane>>4)*4+reg
    const int col = c0 + m;
    const int rowb = r0 + (lane >> 4) * 4;
    const float nc = sqn[col];
    float v0_, v1_, v2_, v3_;
    #pragma unroll
    for (int r = 0; r < 4; ++r) {
        const int row = rowb + r;
        float sq = sqn[row] + nc - 2.f * acc[r];
        float v = (row == col) ? 0.f : -SIGMA * sqrtf(fmaxf(sq, 0.f));
        Fm[(size_t)row * N + col] = v;
        if (r == 0) v0_ = v; else if (r == 1) v1_ = v;
        else if (r == 2) v2_ = v; else v3_ = v;
    }
    // mirror: F[col][rowb..rowb+3] contiguous, 16B-aligned
    *(float4*)(Fm + (size_t)col * N + rowb) = make_float4(v0_, v1_, v2_, v3_);
}

// ---------------------------------------------------------------------------
// Kernel 3 (R2 verbatim): per-row softmax + denom + loss.
// One block (512 threads) per row i; thread t owns column t.
// Row max is exactly 0 (diag F = 0, off-diag < 0) -> no max pass.
// ---------------------------------------------------------------------------
__global__ __launch_bounds__(512, 4)
void row_kernel(const float* __restrict__ Fm,
                const float* __restrict__ label,
                float* __restrict__ out) {
    const int i = blockIdx.x;
    const int t = threadIdx.x;   // 0..511
    const int wave = t >> 6, lane = t & 63;

    __shared__ __align__(16) float Rs[N];
    __shared__ __align__(16) float Ss[N];
    __shared__ float red[8];

    const float li = label[i];
    const float f = Fm[(size_t)i * N + t];
    const float Rk = fabsf(li - label[t]);
    Rs[t] = Rk;

    const float e = __expf(f);

    // Z = sum_j exp(f_j) (includes diagonal, exp(0)=1)
    float s = e;
    #pragma unroll
    for (int off = 32; off > 0; off >>= 1) s += __shfl_xor(s, off);
    if (lane == 0) red[wave] = s;
    __syncthreads();
    const float Z = red[0] + red[1] + red[2] + red[3] +
                    red[4] + red[5] + red[6] + red[7];

    float S = e / Z;
    if (t == i) S = 0.f;         // exclude j==i from all denom sums
    Ss[t] = S;
    __syncthreads();

    // denom[k=t] = sum_j [R[j] >= R[k]] * S[j], float4 LDS broadcasts
    float denom = 0.f;
    const float4* R4 = (const float4*)Rs;
    const float4* S4 = (const float4*)Ss;
    #pragma unroll 16
    for (int j4 = 0; j4 < N / 4; ++j4) {
        float4 r = R4[j4];
        float4 sv = S4[j4];
        denom += (r.x >= Rk) ? sv.x : 0.f;
        denom += (r.y >= Rk) ? sv.y : 0.f;
        denom += (r.z >= Rk) ? sv.z : 0.f;
        denom += (r.w >= Rk) ? sv.w : 0.f;
    }

    float part = (t == i) ? 0.f : (f - __logf(denom + EPS));

    #pragma unroll
    for (int off = 32; off > 0; off >>= 1) part += __shfl_xor(part, off);
    if (lane == 0) red[wave] = part;
    __syncthreads();
    if (t == 0) {
        float tot = red[0] + red[1] + red[2] + red[3] +
                    red[4] + red[5] + red[6] + red[7];
        atomicAdd(out, tot * (-1.f / ((float)N * (float)(N - 1))));
    }
}

// ---------------------------------------------------------------------------
extern "C" void kernel_launch(void* const* d_in, const int* in_sizes, int n_in,
                              void* d_out, int out_size, void* d_ws, size_t ws_size,
                              hipStream_t stream) {
    const float* feature = (const float*)d_in[0];   // [512, 512] f32
    const float* label   = (const float*)d_in[1];   // [512, 1]  f32
    float* out = (float*)d_out;

    float* Fm             = (float*)d_ws;                          // 1 MB
    unsigned short* featb = (unsigned short*)(Fm + (size_t)N * N); // 512 KB
    float* sqn            = (float*)(featb + (size_t)N * N);       // 2 KB

    convert_kernel<<<N, 64, 0, stream>>>(feature, featb, sqn, out);
    fmat_sym_kernel<<<528, 64, 0, stream>>>(featb, sqn, Fm);
    row_kernel<<<N, N, 0, stream>>>(Fm, label, out);
}